// Round 1
// baseline (616.838 us; speedup 1.0000x reference)
//
#include <hip/hip_runtime.h>
#include <math.h>

typedef unsigned short u16;
typedef unsigned int u32;
typedef __attribute__((ext_vector_type(4))) float f32x4;
typedef __attribute__((ext_vector_type(8))) unsigned short u16x8;
typedef __attribute__((ext_vector_type(4))) unsigned short u16x4;
typedef __attribute__((ext_vector_type(8))) __bf16 bf16x8;

#define DEV __device__ __forceinline__

constexpr int S = 2048;
constexpr int HIDDEN = 5120;
constexpr int H = 16;
constexpr int NOPE = 128, ROPE_D = 64, VD = 128;
constexpr int QKD = NOPE + ROPE_D;  // 192
constexpr int QLORA = 1536, KVLORA = 512;
constexpr int KVA_N = KVLORA + ROPE_D;  // 576
// SCALING = 192^-0.5 * (0.1*0.707*ln(40)+1)^2
constexpr float SCALING = 0.11472134f;

DEV u16 f2b(float f) {
  u32 u = __builtin_bit_cast(u32, f);
  u32 r = u + 0x7FFFu + ((u >> 16) & 1u);
  return (u16)(r >> 16);
}
DEV float b2f(u16 h) { return __builtin_bit_cast(float, (u32)h << 16); }

DEV void store_out(float* p, float v) { *p = v; }
DEV void store_out(u16* p, float v) { *p = f2b(v); }

// ---------------- elementwise f32 -> bf16 ----------------
__global__ __launch_bounds__(256) void k_convert(const float* __restrict__ in,
                                                 u16* __restrict__ out, int n) {
  int i = (blockIdx.x * 256 + threadIdx.x) * 4;
  if (i >= n) return;
  f32x4 v = *reinterpret_cast<const f32x4*>(in + i);
  u16x4 o;
  o[0] = f2b(v[0]); o[1] = f2b(v[1]); o[2] = f2b(v[2]); o[3] = f2b(v[3]);
  *reinterpret_cast<u16x4*>(out + i) = o;
}

// ---------------- transpose f32[R][C] -> bf16[C][R] ----------------
__global__ __launch_bounds__(256) void k_transpose(const float* __restrict__ in,
                                                   u16* __restrict__ out, int R, int C) {
  __shared__ float t[32][33];
  int c0 = blockIdx.x * 32, r0 = blockIdx.y * 32;
  int tx = threadIdx.x, ty = threadIdx.y;
  for (int r = ty; r < 32; r += 8)
    t[r][tx] = in[(size_t)(r0 + r) * C + c0 + tx];
  __syncthreads();
  for (int r = ty; r < 32; r += 8)
    out[(size_t)(c0 + r) * R + r0 + tx] = f2b(t[tx][r]);
}

// ---------------- YaRN rope tables ----------------
__global__ __launch_bounds__(256) void k_rope_tables(float* __restrict__ cs,
                                                     float* __restrict__ sn) {
  int idx = blockIdx.x * 256 + threadIdx.x;
  if (idx >= S * 32) return;
  int s = idx >> 5, j = idx & 31;
  double pf = pow(10000.0, (double)j / 32.0);
  double inv_extra = 1.0 / pf;
  double inv_interp = 1.0 / (40.0 * pf);
  double twopi = 6.283185307179586476925286766559;
  double lnb2 = 2.0 * log(10000.0);
  double lowd = floor(64.0 * log(4096.0 / (32.0 * twopi)) / lnb2);
  if (lowd < 0.0) lowd = 0.0;
  double highd = ceil(64.0 * log(4096.0 / twopi) / lnb2);
  if (highd > 63.0) highd = 63.0;
  double denom = highd - lowd;
  if (denom < 0.001) denom = 0.001;
  double ramp = ((double)j - lowd) / denom;
  ramp = ramp < 0.0 ? 0.0 : (ramp > 1.0 ? 1.0 : ramp);
  float invf = (float)(inv_interp * ramp + inv_extra * (1.0 - ramp));
  float fr = (float)s * invf;
  cs[idx] = cosf(fr);
  sn[idx] = sinf(fr);
}

// ---------------- bf16 GEMM: C[M,N] = A[M,K] * BT[N,K]^T ----------------
template <typename OutT>
__global__ __launch_bounds__(256) void k_gemm(const u16* __restrict__ A,
                                              const u16* __restrict__ BT,
                                              OutT* __restrict__ C, int M, int N, int K) {
  __shared__ u16 Al[128][40];
  __shared__ u16 Bl[128][40];
  const int tid = threadIdx.x;
  const int lane = tid & 63, wave = tid >> 6;
  const int wr = wave >> 1, wc = wave & 1;
  const int lr = lane & 15, lk = lane >> 4;
  const int mbase = blockIdx.y * 128, nbase = blockIdx.x * 128;
  const int srow = tid >> 1, skoff = (tid & 1) * 16;
  f32x4 acc[4][4];
#pragma unroll
  for (int mf = 0; mf < 4; ++mf)
#pragma unroll
    for (int nf = 0; nf < 4; ++nf) acc[mf][nf] = {0.f, 0.f, 0.f, 0.f};

  const u16x8 zz = {0, 0, 0, 0, 0, 0, 0, 0};
  for (int k0 = 0; k0 < K; k0 += 32) {
    const u16* ap = A + (size_t)(mbase + srow) * K + k0 + skoff;
    u16x8 a0 = *reinterpret_cast<const u16x8*>(ap);
    u16x8 a1 = *reinterpret_cast<const u16x8*>(ap + 8);
    u16x8 b0 = zz, b1 = zz;
    if (nbase + srow < N) {
      const u16* bp = BT + (size_t)(nbase + srow) * K + k0 + skoff;
      b0 = *reinterpret_cast<const u16x8*>(bp);
      b1 = *reinterpret_cast<const u16x8*>(bp + 8);
    }
    __syncthreads();  // protect previous iteration's LDS reads
    *reinterpret_cast<u16x8*>(&Al[srow][skoff]) = a0;
    *reinterpret_cast<u16x8*>(&Al[srow][skoff + 8]) = a1;
    *reinterpret_cast<u16x8*>(&Bl[srow][skoff]) = b0;
    *reinterpret_cast<u16x8*>(&Bl[srow][skoff + 8]) = b1;
    __syncthreads();
    bf16x8 af[4], bfr[4];
#pragma unroll
    for (int mf = 0; mf < 4; ++mf)
      af[mf] = *reinterpret_cast<const bf16x8*>(&Al[wr * 64 + mf * 16 + lr][lk * 8]);
#pragma unroll
    for (int nf = 0; nf < 4; ++nf)
      bfr[nf] = *reinterpret_cast<const bf16x8*>(&Bl[wc * 64 + nf * 16 + lr][lk * 8]);
#pragma unroll
    for (int mf = 0; mf < 4; ++mf)
#pragma unroll
      for (int nf = 0; nf < 4; ++nf)
        acc[mf][nf] = __builtin_amdgcn_mfma_f32_16x16x32_bf16(af[mf], bfr[nf], acc[mf][nf], 0, 0, 0);
  }
#pragma unroll
  for (int mf = 0; mf < 4; ++mf)
#pragma unroll
    for (int nf = 0; nf < 4; ++nf) {
      int col = nbase + wc * 64 + nf * 16 + lr;
      if (col < N) {
#pragma unroll
        for (int r = 0; r < 4; ++r) {
          int row = mbase + wr * 64 + mf * 16 + lk * 4 + r;
          store_out(&C[(size_t)row * N + col], acc[mf][nf][r]);
        }
      }
    }
}

// ---------------- RMSNorm fp32 -> bf16 ----------------
__global__ __launch_bounds__(256) void k_rmsnorm(const float* __restrict__ x,
                                                 const float* __restrict__ w,
                                                 u16* __restrict__ y, int ncols, int instride) {
  int row = blockIdx.x, tid = threadIdx.x;
  const float* xr = x + (size_t)row * instride;
  float ss = 0.f;
  for (int i = tid * 4; i < ncols; i += 1024) {
    f32x4 v = *reinterpret_cast<const f32x4*>(xr + i);
    ss += v[0] * v[0] + v[1] * v[1] + v[2] * v[2] + v[3] * v[3];
  }
  for (int off = 32; off > 0; off >>= 1) ss += __shfl_down(ss, off);
  __shared__ float red[4];
  if ((tid & 63) == 0) red[tid >> 6] = ss;
  __syncthreads();
  ss = red[0] + red[1] + red[2] + red[3];
  float sc = rsqrtf(ss / (float)ncols + 1e-6f);
  u16* yr = y + (size_t)row * ncols;
  for (int i = tid * 4; i < ncols; i += 1024) {
    f32x4 v = *reinterpret_cast<const f32x4*>(xr + i);
    u16x4 o;
    o[0] = f2b(v[0] * sc * w[i]);
    o[1] = f2b(v[1] * sc * w[i + 1]);
    o[2] = f2b(v[2] * sc * w[i + 2]);
    o[3] = f2b(v[3] * sc * w[i + 3]);
    *reinterpret_cast<u16x4*>(yr + i) = o;
  }
}

// ---------------- build qf [H][S][192], kf [H][S][192] with RoPE ----------------
__global__ __launch_bounds__(256) void k_build_qkf(const u16* __restrict__ qn,
                                                   const u16* __restrict__ kv,
                                                   const float* __restrict__ latent,
                                                   const float* __restrict__ cs,
                                                   const float* __restrict__ sn,
                                                   u16* __restrict__ qf, u16* __restrict__ kf) {
  int s = blockIdx.x, tid = threadIdx.x;
  for (int idx = tid; idx < H * NOPE; idx += 256) {
    int h = idx >> 7, dd = idx & 127;
    qf[((size_t)h * S + s) * QKD + dd] = qn[(size_t)s * (H * QKD) + h * QKD + dd];
    kf[((size_t)h * S + s) * QKD + dd] = kv[(size_t)s * (H * 256) + h * 256 + dd];
  }
  for (int idx = tid; idx < H * 32; idx += 256) {
    int h = idx >> 5, j = idx & 31;
    float c = cs[s * 32 + j], si = sn[s * 32 + j];
    float x1 = b2f(qn[(size_t)s * (H * QKD) + h * QKD + NOPE + 2 * j]);
    float x2 = b2f(qn[(size_t)s * (H * QKD) + h * QKD + NOPE + 2 * j + 1]);
    qf[((size_t)h * S + s) * QKD + NOPE + 2 * j] = f2b(x1 * c - x2 * si);
    qf[((size_t)h * S + s) * QKD + NOPE + 2 * j + 1] = f2b(x2 * c + x1 * si);
    float k1 = latent[(size_t)s * KVA_N + KVLORA + 2 * j];
    float k2 = latent[(size_t)s * KVA_N + KVLORA + 2 * j + 1];
    kf[((size_t)h * S + s) * QKD + NOPE + 2 * j] = f2b(k1 * c - k2 * si);
    kf[((size_t)h * S + s) * QKD + NOPE + 2 * j + 1] = f2b(k2 * c + k1 * si);
  }
}

// ---------------- build vt [H][128][S] (transposed V) ----------------
__global__ void k_build_vt(const u16* __restrict__ kv, u16* __restrict__ vt) {
  __shared__ u16 t[32][33];
  int s0 = blockIdx.x * 32, d0 = blockIdx.y * 32, h = blockIdx.z;
  int tx = threadIdx.x, ty = threadIdx.y;
  for (int r = ty; r < 32; r += 8)
    t[r][tx] = kv[(size_t)(s0 + r) * (H * 256) + h * 256 + NOPE + d0 + tx];
  __syncthreads();
  for (int r = ty; r < 32; r += 8)
    vt[((size_t)h * VD + d0 + r) * S + s0 + tx] = t[tx][r];
}

// ---------------- flash attention (causal), per head ----------------
__global__ __launch_bounds__(256) void k_attn(const u16* __restrict__ qf,
                                              const u16* __restrict__ kf,
                                              const u16* __restrict__ vt,
                                              u16* __restrict__ attn) {
  const int h = blockIdx.y;
  const int qt = blockIdx.x;
  const int qbase = qt * 64;
  const int tid = threadIdx.x, wave = tid >> 6, lane = tid & 63;
  const int lr = lane & 15, lk = lane >> 4;
  __shared__ u16 Kl[64][200];
  __shared__ u16 Vl[128][72];
  __shared__ u16 Pl[4][16][72];

  bf16x8 qfrag[6];
  const u16* qrow = qf + ((size_t)h * S + qbase + wave * 16 + lr) * QKD;
#pragma unroll
  for (int d = 0; d < 6; ++d)
    qfrag[d] = *reinterpret_cast<const bf16x8*>(qrow + d * 32 + lk * 8);

  f32x4 o[8];
#pragma unroll
  for (int f = 0; f < 8; ++f) o[f] = {0.f, 0.f, 0.f, 0.f};
  float m_[4] = {-__builtin_inff(), -__builtin_inff(), -__builtin_inff(), -__builtin_inff()};
  float l_[4] = {0.f, 0.f, 0.f, 0.f};

  const int ktiles = qt + 1;
  for (int kt = 0; kt < ktiles; ++kt) {
    const int kbase = kt * 64;
    // stage K tile [64][192]
    for (int c = tid; c < 64 * 24; c += 256) {
      int row = c / 24, off = (c % 24) * 8;
      *reinterpret_cast<u16x8*>(&Kl[row][off]) =
          *reinterpret_cast<const u16x8*>(kf + ((size_t)h * S + kbase + row) * QKD + off);
    }
    // stage VT tile [128][64]
    for (int c = tid; c < 128 * 8; c += 256) {
      int row = c >> 3, off = (c & 7) * 8;
      *reinterpret_cast<u16x8*>(&Vl[row][off]) =
          *reinterpret_cast<const u16x8*>(vt + ((size_t)h * VD + row) * S + kbase + off);
    }
    __syncthreads();

    // QK^T : S[16 x 64]
    f32x4 sacc[4];
#pragma unroll
    for (int nf = 0; nf < 4; ++nf) sacc[nf] = {0.f, 0.f, 0.f, 0.f};
#pragma unroll
    for (int nf = 0; nf < 4; ++nf)
#pragma unroll
      for (int dk = 0; dk < 6; ++dk) {
        bf16x8 b = *reinterpret_cast<const bf16x8*>(&Kl[nf * 16 + lr][dk * 32 + lk * 8]);
        sacc[nf] = __builtin_amdgcn_mfma_f32_16x16x32_bf16(qfrag[dk], b, sacc[nf], 0, 0, 0);
      }

    // scale + causal mask + online softmax
    float sv[4][4];
    float rowmax[4] = {-__builtin_inff(), -__builtin_inff(), -__builtin_inff(), -__builtin_inff()};
#pragma unroll
    for (int nf = 0; nf < 4; ++nf) {
      int kcol = kbase + nf * 16 + lr;
#pragma unroll
      for (int r = 0; r < 4; ++r) {
        float v = sacc[nf][r] * SCALING;
        int qrow_g = qbase + wave * 16 + lk * 4 + r;
        if (kcol > qrow_g) v = -__builtin_inff();
        sv[nf][r] = v;
        rowmax[r] = fmaxf(rowmax[r], v);
      }
    }
#pragma unroll
    for (int r = 0; r < 4; ++r) {
#pragma unroll
      for (int off = 1; off < 16; off <<= 1)
        rowmax[r] = fmaxf(rowmax[r], __shfl_xor(rowmax[r], off));
    }
    float alpha[4], rowsum[4] = {0.f, 0.f, 0.f, 0.f};
#pragma unroll
    for (int r = 0; r < 4; ++r) {
      float mn = fmaxf(m_[r], rowmax[r]);
      alpha[r] = __expf(m_[r] - mn);
      m_[r] = mn;
    }
#pragma unroll
    for (int nf = 0; nf < 4; ++nf)
#pragma unroll
      for (int r = 0; r < 4; ++r) {
        float p = __expf(sv[nf][r] - m_[r]);
        sv[nf][r] = p;
        rowsum[r] += p;
      }
#pragma unroll
    for (int r = 0; r < 4; ++r) {
#pragma unroll
      for (int off = 1; off < 16; off <<= 1) rowsum[r] += __shfl_xor(rowsum[r], off);
      l_[r] = l_[r] * alpha[r] + rowsum[r];
    }
    // write P (C-layout) to LDS, rescale O
#pragma unroll
    for (int nf = 0; nf < 4; ++nf)
#pragma unroll
      for (int r = 0; r < 4; ++r) Pl[wave][lk * 4 + r][nf * 16 + lr] = f2b(sv[nf][r]);
#pragma unroll
    for (int f = 0; f < 8; ++f)
#pragma unroll
      for (int r = 0; r < 4; ++r) o[f][r] *= alpha[r];

    // PV : O[16 x 128] += P[16 x 64] * V[64 x 128]
#pragma unroll
    for (int kk = 0; kk < 2; ++kk) {
      bf16x8 pa = *reinterpret_cast<const bf16x8*>(&Pl[wave][lr][kk * 32 + lk * 8]);
#pragma unroll
      for (int f = 0; f < 8; ++f) {
        bf16x8 b = *reinterpret_cast<const bf16x8*>(&Vl[f * 16 + lr][kk * 32 + lk * 8]);
        o[f] = __builtin_amdgcn_mfma_f32_16x16x32_bf16(pa, b, o[f], 0, 0, 0);
      }
    }
    __syncthreads();
  }

  // epilogue: normalize and store
#pragma unroll
  for (int f = 0; f < 8; ++f)
#pragma unroll
    for (int r = 0; r < 4; ++r) {
      int row = qbase + wave * 16 + lk * 4 + r;
      float val = o[f][r] / l_[r];
      attn[(size_t)row * (H * VD) + h * VD + f * 16 + lr] = f2b(val);
    }
}

// ---------------- host launch ----------------
extern "C" void kernel_launch(void* const* d_in, const int* in_sizes, int n_in,
                              void* d_out, int out_size, void* d_ws, size_t ws_size,
                              hipStream_t stream) {
  (void)in_sizes; (void)n_in; (void)out_size; (void)ws_size;
  const float* hidden    = (const float*)d_in[1];
  const float* w_q_a     = (const float*)d_in[2];
  const float* q_a_ln_w  = (const float*)d_in[3];
  const float* w_q_b     = (const float*)d_in[4];
  const float* w_kv_a    = (const float*)d_in[5];
  const float* kv_a_ln_w = (const float*)d_in[6];
  const float* w_kv_b    = (const float*)d_in[7];
  const float* w_o       = (const float*)d_in[8];
  float* out = (float*)d_out;

  char* ws = (char*)d_ws;
  size_t off = 0;
  auto alloc = [&](size_t bytes) {
    size_t o = off;
    off += (bytes + 255) & ~(size_t)255;
    return o;
  };
  size_t o_hs    = alloc((size_t)S * HIDDEN * 2);        // hs bf16; later reused as qf
  size_t o_btqa  = alloc((size_t)QLORA * HIDDEN * 2);    // later reused (with o_btkva) as bt_o
  size_t o_btkva = alloc((size_t)KVA_N * HIDDEN * 2);
  size_t o_btqb  = alloc((size_t)(H * QKD) * QLORA * 2);
  size_t o_btkvb = alloc((size_t)(H * 256) * KVLORA * 2);
  size_t o_qlat  = alloc((size_t)S * QLORA * 4);         // later reused as attn
  size_t o_lat   = alloc((size_t)S * KVA_N * 4);
  size_t o_qln   = alloc((size_t)S * QLORA * 2);
  size_t o_kvln  = alloc((size_t)S * KVLORA * 2);
  size_t o_qn    = alloc((size_t)S * (H * QKD) * 2);
  size_t o_kv    = alloc((size_t)S * (H * 256) * 2);
  size_t o_kf    = alloc((size_t)H * S * QKD * 2);
  size_t o_vt    = alloc((size_t)H * VD * S * 2);
  size_t o_cs    = alloc((size_t)S * 32 * 4);
  size_t o_sn    = alloc((size_t)S * 32 * 4);

  u16* hs_bf  = (u16*)(ws + o_hs);
  u16* bt_qa  = (u16*)(ws + o_btqa);
  u16* bt_kva = (u16*)(ws + o_btkva);
  u16* bt_qb  = (u16*)(ws + o_btqb);
  u16* bt_kvb = (u16*)(ws + o_btkvb);
  float* q_lat  = (float*)(ws + o_qlat);
  float* latent = (float*)(ws + o_lat);
  u16* q_ln  = (u16*)(ws + o_qln);
  u16* kv_ln = (u16*)(ws + o_kvln);
  u16* qn    = (u16*)(ws + o_qn);
  u16* kvb   = (u16*)(ws + o_kv);
  u16* kf    = (u16*)(ws + o_kf);
  u16* vt    = (u16*)(ws + o_vt);
  float* cs = (float*)(ws + o_cs);
  float* sn = (float*)(ws + o_sn);
  // aliases (lifetimes verified: source buffers dead before alias written)
  u16* qf   = (u16*)(ws + o_hs);
  u16* bt_o = (u16*)(ws + o_btqa);
  u16* attn = (u16*)(ws + o_qlat);

  dim3 t256(256), t32x8(32, 8);

  // prep
  k_convert<<<(S * HIDDEN / 4 + 255) / 256, t256, 0, stream>>>(hidden, hs_bf, S * HIDDEN);
  k_transpose<<<dim3(QLORA / 32, HIDDEN / 32), t32x8, 0, stream>>>(w_q_a, bt_qa, HIDDEN, QLORA);
  k_transpose<<<dim3(KVA_N / 32, HIDDEN / 32), t32x8, 0, stream>>>(w_kv_a, bt_kva, HIDDEN, KVA_N);
  k_transpose<<<dim3(H * QKD / 32, QLORA / 32), t32x8, 0, stream>>>(w_q_b, bt_qb, QLORA, H * QKD);
  k_transpose<<<dim3(H * 256 / 32, KVLORA / 32), t32x8, 0, stream>>>(w_kv_b, bt_kvb, KVLORA, H * 256);
  k_rope_tables<<<(S * 32 + 255) / 256, t256, 0, stream>>>(cs, sn);

  // down-projections
  k_gemm<float><<<dim3(QLORA / 128, S / 128), t256, 0, stream>>>(hs_bf, bt_qa, q_lat, S, QLORA, HIDDEN);
  k_gemm<float><<<dim3((KVA_N + 127) / 128, S / 128), t256, 0, stream>>>(hs_bf, bt_kva, latent, S, KVA_N, HIDDEN);

  // norms
  k_rmsnorm<<<S, t256, 0, stream>>>(q_lat, q_a_ln_w, q_ln, QLORA, QLORA);
  k_rmsnorm<<<S, t256, 0, stream>>>(latent, kv_a_ln_w, kv_ln, KVLORA, KVA_N);

  // up-projections (bf16 outputs)
  k_gemm<u16><<<dim3(H * QKD / 128, S / 128), t256, 0, stream>>>(q_ln, bt_qb, qn, S, H * QKD, QLORA);
  k_gemm<u16><<<dim3(H * 256 / 128, S / 128), t256, 0, stream>>>(kv_ln, bt_kvb, kvb, S, H * 256, KVLORA);

  // rearrange + RoPE
  k_build_qkf<<<S, t256, 0, stream>>>(qn, kvb, latent, cs, sn, qf, kf);
  k_build_vt<<<dim3(S / 32, VD / 32, H), t32x8, 0, stream>>>(kvb, vt);

  // transpose w_o (into region freed after down-projections)
  k_transpose<<<dim3(HIDDEN / 32, (H * VD) / 32), t32x8, 0, stream>>>(w_o, bt_o, H * VD, HIDDEN);

  // attention
  k_attn<<<dim3(S / 64, H), t256, 0, stream>>>(qf, kf, vt, attn);

  // output projection
  k_gemm<float><<<dim3(HIDDEN / 128, S / 128), t256, 0, stream>>>(attn, bt_o, out, S, HIDDEN, H * VD);
}